// Round 1
// baseline (921.035 us; speedup 1.0000x reference)
//
#include <hip/hip_runtime.h>

#define N_NODES  131072
#define G_GRAPHS 1024
#define NPG0     128
#define HDIM     128
#define E_EDGES  2097152
#define EPG      2048           // edges per graph (NPG0 * DEG)
#define BN_EPS   1e-5f
#define INV_SQRT2 0.70710678118654752440f

__device__ __forceinline__ float wred_sum(float v) {
  v += __shfl_xor(v, 8);
  v += __shfl_xor(v, 16);
  v += __shfl_xor(v, 32);
  return v;
}

// Compute BN scale/shift coefs from raw (sum, sumsq) stats into LDS.
// Threads t<128 participate; caller must __syncthreads() after.
__device__ __forceinline__ void bn_coefs(const float* __restrict__ stats,
                                         const float* __restrict__ gamma,
                                         const float* __restrict__ beta,
                                         float inv_n, float* cA, float* cC, int t) {
  if (t < HDIM) {
    float s  = stats[t];
    float ss = stats[HDIM + t];
    float m  = s * inv_n;
    float var = fmaxf(ss * inv_n - m * m, 0.f);
    float a = gamma[t] * rsqrtf(var + BN_EPS);
    cA[t] = a;
    cC[t] = beta[t] - m * a;
  }
}

// y = act(in) @ W + bias ; accumulate column sum/sumsq of y into outStats.
// act(v) = relu(aA[k]*v + aC[k]) computed from actStats (ACT=1) else identity.
// Block: 512 threads, 128 rows per block. W: [128][128] row-major.
template <int ACT>
__global__ __launch_bounds__(512, 4)
void k_gemm(const float* __restrict__ in, float* __restrict__ out,
            const float* __restrict__ W, const float* __restrict__ bias,
            const float* __restrict__ actStats, const float* __restrict__ actG,
            const float* __restrict__ actB, float act_inv_n,
            float* __restrict__ outStats) {
  __shared__ float Wl[HDIM * HDIM];
  __shared__ float sred[2 * HDIM];
  __shared__ float aA[HDIM], aC[HDIM];
  const int t = threadIdx.x;

  const float4* Wg = (const float4*)W;
  float4* Wl4 = (float4*)Wl;
  #pragma unroll 4
  for (int u = t; u < HDIM * HDIM / 4; u += 512) Wl4[u] = Wg[u];
  if (t < 2 * HDIM) sred[t] = 0.f;
  if (ACT) bn_coefs(actStats, actG, actB, act_inv_n, aA, aC, t);
  __syncthreads();

  const int q  = t & 7;     // channel group: c = q*4 + 32*j + comp
  const int rg = t >> 3;    // 0..63 row group (2 rows each)
  const size_t row0 = (size_t)blockIdx.x * 128 + (size_t)rg * 2;
  const float* x0 = in + row0 * HDIM;
  const float* x1 = x0 + HDIM;

  float4 acc0[4], acc1[4];
  #pragma unroll
  for (int j = 0; j < 4; ++j) {
    acc0[j] = make_float4(0.f, 0.f, 0.f, 0.f);
    acc1[j] = make_float4(0.f, 0.f, 0.f, 0.f);
  }

  for (int k = 0; k < HDIM; k += 4) {
    float4 xa = *(const float4*)(x0 + k);
    float4 xb = *(const float4*)(x1 + k);
    if (ACT) {
      xa.x = fmaxf(fmaf(aA[k + 0], xa.x, aC[k + 0]), 0.f);
      xa.y = fmaxf(fmaf(aA[k + 1], xa.y, aC[k + 1]), 0.f);
      xa.z = fmaxf(fmaf(aA[k + 2], xa.z, aC[k + 2]), 0.f);
      xa.w = fmaxf(fmaf(aA[k + 3], xa.w, aC[k + 3]), 0.f);
      xb.x = fmaxf(fmaf(aA[k + 0], xb.x, aC[k + 0]), 0.f);
      xb.y = fmaxf(fmaf(aA[k + 1], xb.y, aC[k + 1]), 0.f);
      xb.z = fmaxf(fmaf(aA[k + 2], xb.z, aC[k + 2]), 0.f);
      xb.w = fmaxf(fmaf(aA[k + 3], xb.w, aC[k + 3]), 0.f);
    }
    #pragma unroll
    for (int j = 0; j < 4; ++j) {
      float4 w0 = Wl4[(k + 0) * 32 + q + 8 * j];
      float4 w1 = Wl4[(k + 1) * 32 + q + 8 * j];
      float4 w2 = Wl4[(k + 2) * 32 + q + 8 * j];
      float4 w3 = Wl4[(k + 3) * 32 + q + 8 * j];
      acc0[j].x += xa.x * w0.x + xa.y * w1.x + xa.z * w2.x + xa.w * w3.x;
      acc0[j].y += xa.x * w0.y + xa.y * w1.y + xa.z * w2.y + xa.w * w3.y;
      acc0[j].z += xa.x * w0.z + xa.y * w1.z + xa.z * w2.z + xa.w * w3.z;
      acc0[j].w += xa.x * w0.w + xa.y * w1.w + xa.z * w2.w + xa.w * w3.w;
      acc1[j].x += xb.x * w0.x + xb.y * w1.x + xb.z * w2.x + xb.w * w3.x;
      acc1[j].y += xb.x * w0.y + xb.y * w1.y + xb.z * w2.y + xb.w * w3.y;
      acc1[j].z += xb.x * w0.z + xb.y * w1.z + xb.z * w2.z + xb.w * w3.z;
      acc1[j].w += xb.x * w0.w + xb.y * w1.w + xb.z * w2.w + xb.w * w3.w;
    }
  }

  float* o0 = out + row0 * HDIM;
  float* o1 = o0 + HDIM;
  #pragma unroll
  for (int j = 0; j < 4; ++j) {
    const int cbase = q * 4 + 32 * j;
    float4 b4 = *(const float4*)(bias + cbase);
    float4 y0, y1;
    y0.x = acc0[j].x + b4.x; y0.y = acc0[j].y + b4.y;
    y0.z = acc0[j].z + b4.z; y0.w = acc0[j].w + b4.w;
    y1.x = acc1[j].x + b4.x; y1.y = acc1[j].y + b4.y;
    y1.z = acc1[j].z + b4.z; y1.w = acc1[j].w + b4.w;
    *(float4*)(o0 + cbase) = y0;
    *(float4*)(o1 + cbase) = y1;
    // column stats (sum, sumsq) over the block's 128 rows
    float s0 = wred_sum(y0.x + y1.x), q0 = wred_sum(y0.x * y0.x + y1.x * y1.x);
    float s1 = wred_sum(y0.y + y1.y), q1 = wred_sum(y0.y * y0.y + y1.y * y1.y);
    float s2 = wred_sum(y0.z + y1.z), q2 = wred_sum(y0.z * y0.z + y1.z * y1.z);
    float s3 = wred_sum(y0.w + y1.w), q3 = wred_sum(y0.w * y0.w + y1.w * y1.w);
    if ((t & 56) == 0) {  // one lane per q per wave
      atomicAdd(&sred[cbase + 0], s0); atomicAdd(&sred[HDIM + cbase + 0], q0);
      atomicAdd(&sred[cbase + 1], s1); atomicAdd(&sred[HDIM + cbase + 1], q1);
      atomicAdd(&sred[cbase + 2], s2); atomicAdd(&sred[HDIM + cbase + 2], q2);
      atomicAdd(&sred[cbase + 3], s3); atomicAdd(&sred[HDIM + cbase + 3], q3);
    }
  }
  __syncthreads();
  if (t < 2 * HDIM) atomicAdd(&outStats[t], sred[t]);
}

// Per-graph GIN aggregation: h = act(x) + sum_{e: dst==d} act(x[src]).
// One block per graph; node features staged in LDS; per-dst CSR built in LDS.
// act applied iff actStats != nullptr (layer 0 normalizes lin_start output).
__global__ __launch_bounds__(512, 2)
void k_agg(const float* __restrict__ xin_g, float* __restrict__ hout,
           const int* __restrict__ esrc, const int* __restrict__ edst,
           int shift, int npg,
           const float* __restrict__ actStats, const float* __restrict__ actG,
           const float* __restrict__ actB, float act_inv_n) {
  __shared__ float xs[NPG0 * HDIM];   // 64 KB
  __shared__ int   srcs[EPG];         // 8 KB
  __shared__ int   cnt[NPG0], off[NPG0], cur[NPG0];
  __shared__ float aA[HDIM], aC[HDIM];
  const int t = threadIdx.x;
  const int g = blockIdx.x;
  const bool act = (actStats != nullptr);

  if (act) bn_coefs(actStats, actG, actB, act_inv_n, aA, aC, t);
  for (int j = t; j < npg; j += 512) { cnt[j] = 0; cur[j] = 0; }
  __syncthreads();

  // stage activated node features
  const float4* xg = (const float4*)(xin_g + (size_t)g * npg * HDIM);
  float4* xs4 = (float4*)xs;
  for (int u = t; u < npg * (HDIM / 4); u += 512) {
    float4 v = xg[u];
    if (act) {
      int c = (u & 31) * 4;
      v.x = fmaxf(fmaf(aA[c + 0], v.x, aC[c + 0]), 0.f);
      v.y = fmaxf(fmaf(aA[c + 1], v.y, aC[c + 1]), 0.f);
      v.z = fmaxf(fmaf(aA[c + 2], v.z, aC[c + 2]), 0.f);
      v.w = fmaxf(fmaf(aA[c + 3], v.w, aC[c + 3]), 0.f);
    }
    xs4[u] = v;
  }
  // count in-degree
  const int ebase = g * EPG;
  for (int e = t; e < EPG; e += 512) {
    int d = (edst[ebase + e] >> shift) - g * npg;
    atomicAdd(&cnt[d], 1);
  }
  __syncthreads();
  if (t == 0) {
    int s = 0;
    for (int j = 0; j < npg; ++j) { off[j] = s; s += cnt[j]; }
  }
  __syncthreads();
  // scatter src ids grouped by dst
  for (int e = t; e < EPG; e += 512) {
    int d  = (edst[ebase + e] >> shift) - g * npg;
    int sl = (esrc[ebase + e] >> shift) - g * npg;
    int p = off[d] + atomicAdd(&cur[d], 1);
    srcs[p] = sl;
  }
  __syncthreads();
  // aggregate (conflict-free: lanes own consecutive channels of one dst)
  const int c  = t & 127;
  const int db = t >> 7;   // 0..3
  float* hbase = hout + (size_t)g * npg * HDIM;
  for (int d = db; d < npg; d += 4) {
    float acc = xs[d * HDIM + c];
    const int o = off[d], e2 = off[d] + cnt[d];
    for (int e = o; e < e2; ++e) acc += xs[srcs[e] * HDIM + c];
    hbase[d * HDIM + c] = acc;
  }
}

// x' = pairwise-haar(act(h)) ; emb[g] = per-graph sum of x' ; embd col-stats.
__global__ __launch_bounds__(256, 4)
void k_pool(const float* __restrict__ hin, float* __restrict__ xout,
            float* __restrict__ emb, int layer, int npg_in,
            const float* __restrict__ actStats, const float* __restrict__ actG,
            const float* __restrict__ actB, float act_inv_n,
            float* __restrict__ embStats) {
  __shared__ float aA[HDIM], aC[HDIM];
  __shared__ float red[256];
  const int t = threadIdx.x;
  const int g = blockIdx.x;
  bn_coefs(actStats, actG, actB, act_inv_n, aA, aC, t);
  __syncthreads();
  const int c = t & 127;
  const int ph = t >> 7;
  const int npg_out = npg_in >> 1;
  const float* hb = hin + (size_t)g * npg_in * HDIM;
  float* xb = xout + (size_t)g * npg_out * HDIM;
  const float a = aA[c], cc = aC[c];
  float es = 0.f;
  for (int p = ph; p < npg_out; p += 2) {
    float v0 = fmaxf(fmaf(a, hb[(2 * p    ) * HDIM + c], cc), 0.f);
    float v1 = fmaxf(fmaf(a, hb[(2 * p + 1) * HDIM + c], cc), 0.f);
    float xv = (v0 + v1) * INV_SQRT2;
    xb[p * HDIM + c] = xv;
    es += xv;
  }
  red[t] = es;
  __syncthreads();
  if (t < HDIM) {
    float e = red[t] + red[t + HDIM];
    emb[(size_t)g * 384 + layer * HDIM + t] = e;
    atomicAdd(&embStats[t], e);
    atomicAdd(&embStats[HDIM + t], e * e);
  }
}

// out[g] = relu(bne(emb[g])) @ lin_w + lin_b
__global__ __launch_bounds__(128, 8)
void k_final(const float* __restrict__ emb,
             const float* __restrict__ se0, const float* __restrict__ se1,
             const float* __restrict__ se2,
             const float* __restrict__ bneG, const float* __restrict__ bneB,
             const float* __restrict__ linW, const float* __restrict__ linB,
             float* __restrict__ outp) {
  __shared__ float ev[384];
  __shared__ float eA[384], eC[384];
  const int t = threadIdx.x;
  const int g = blockIdx.x;
  if (t < 128) {
    const float* se[3] = {se0, se1, se2};
    const float inv_n = 1.f / (float)G_GRAPHS;
    #pragma unroll
    for (int l = 0; l < 3; ++l) {
      float s  = se[l][t];
      float ss = se[l][128 + t];
      float m  = s * inv_n;
      float var = fmaxf(ss * inv_n - m * m, 0.f);
      float a = bneG[l * 128 + t] * rsqrtf(var + BN_EPS);
      eA[l * 128 + t] = a;
      eC[l * 128 + t] = bneB[l * 128 + t] - m * a;
    }
  }
  __syncthreads();
  for (int j = t; j < 384; j += 128)
    ev[j] = fmaxf(fmaf(eA[j], emb[(size_t)g * 384 + j], eC[j]), 0.f);
  __syncthreads();
  if (t < 10) {
    float acc = linB[t];
    #pragma unroll 8
    for (int j = 0; j < 384; ++j) acc += ev[j] * linW[j * 10 + t];
    outp[g * 10 + t] = acc;
  }
}

extern "C" void kernel_launch(void* const* d_in, const int* in_sizes, int n_in,
                              void* d_out, int out_size, void* d_ws, size_t ws_size,
                              hipStream_t stream) {
  const float* x           = (const float*)d_in[0];
  const int*   ei          = (const int*)  d_in[1];
  const float* lin_start_w = (const float*)d_in[2];
  const float* lin_start_b = (const float*)d_in[3];
  const float* bn_start_g  = (const float*)d_in[4];
  const float* bn_start_b  = (const float*)d_in[5];
  const float* conv_w1     = (const float*)d_in[6];
  const float* conv_b1     = (const float*)d_in[7];
  const float* conv_bn_g   = (const float*)d_in[8];
  const float* conv_bn_b   = (const float*)d_in[9];
  const float* conv_w2     = (const float*)d_in[10];
  const float* conv_b2     = (const float*)d_in[11];
  const float* bn_g        = (const float*)d_in[12];
  const float* bn_b        = (const float*)d_in[13];
  const float* bne_g       = (const float*)d_in[14];
  const float* bne_b       = (const float*)d_in[15];
  const float* lin_w       = (const float*)d_in[16];
  const float* lin_b       = (const float*)d_in[17];
  float* outp = (float*)d_out;

  float* ws = (float*)d_ws;
  const size_t NH = (size_t)N_NODES * HDIM;
  float* buf0  = ws;
  float* buf1  = ws + NH;
  float* emb   = ws + 2 * NH;                     // G * 384
  float* stats = emb + (size_t)G_GRAPHS * 384;    // 10 slots * 256 floats
  // slots: 0: bn_start; per layer i: 1+3i: conv_bn, 2+3i: bn, 3+3i: bne

  hipMemsetAsync(stats, 0, 10 * 256 * sizeof(float), stream);

  const int* esrc = ei;
  const int* edst = ei + E_EDGES;

  // stage A: y0 = x @ lin_start_w + b  (stats -> slot 0)
  k_gemm<0><<<N_NODES / 128, 512, 0, stream>>>(
      x, buf0, lin_start_w, lin_start_b, nullptr, nullptr, nullptr, 0.f, stats);

  for (int i = 0; i < 3; ++i) {
    const int n   = N_NODES >> i;
    const int npg = NPG0 >> i;
    const float inv_n = 1.f / (float)n;
    float* s1 = stats + (1 + 3 * i) * 256;
    float* s2 = stats + (2 + 3 * i) * 256;
    float* se = stats + (3 + 3 * i) * 256;

    // h = act(x) + aggregate(act(x))  (act only at layer 0: bn_start+relu)
    k_agg<<<G_GRAPHS, 512, 0, stream>>>(
        buf0, buf1, esrc, edst, i, npg,
        (i == 0) ? stats : nullptr, bn_start_g, bn_start_b, 1.f / (float)N_NODES);
    // h1 = h @ w1 + b1 (stats -> s1)
    k_gemm<0><<<n / 128, 512, 0, stream>>>(
        buf1, buf0, conv_w1 + (size_t)i * HDIM * HDIM, conv_b1 + i * HDIM,
        nullptr, nullptr, nullptr, 0.f, s1);
    // h2 = relu(bn(h1)) @ w2 + b2 (stats -> s2)
    k_gemm<1><<<n / 128, 512, 0, stream>>>(
        buf0, buf1, conv_w2 + (size_t)i * HDIM * HDIM, conv_b2 + i * HDIM,
        s1, conv_bn_g + i * HDIM, conv_bn_b + i * HDIM, inv_n, s2);
    // x' = haar(relu(bn(h2))) ; emb col i ; embd stats -> se
    k_pool<<<G_GRAPHS, 256, 0, stream>>>(
        buf1, buf0, emb, i, npg,
        s2, bn_g + i * HDIM, bn_b + i * HDIM, inv_n, se);
  }

  k_final<<<G_GRAPHS, 128, 0, stream>>>(
      emb, stats + 3 * 256, stats + 6 * 256, stats + 9 * 256,
      bne_g, bne_b, lin_w, lin_b, outp);
}

// Round 2
// 602.885 us; speedup vs baseline: 1.5277x; 1.5277x over previous
//
#include <hip/hip_runtime.h>

#define N_NODES  131072
#define G_GRAPHS 1024
#define NPG0     128
#define HDIM     128
#define E_EDGES  2097152
#define EPG      2048           // edges per graph (NPG0 * DEG)
#define BN_EPS   1e-5f
#define INV_SQRT2 0.70710678118654752440f

__device__ __forceinline__ float wred_sum(float v) {
  v += __shfl_xor(v, 8);
  v += __shfl_xor(v, 16);
  v += __shfl_xor(v, 32);
  return v;
}

// Compute BN scale/shift coefs from raw (sum, sumsq) stats into LDS.
// Threads t<128 participate; caller must __syncthreads() after.
__device__ __forceinline__ void bn_coefs(const float* __restrict__ stats,
                                         const float* __restrict__ gamma,
                                         const float* __restrict__ beta,
                                         float inv_n, float* cA, float* cC, int t) {
  if (t < HDIM) {
    float s  = stats[t];
    float ss = stats[HDIM + t];
    float m  = s * inv_n;
    float var = fmaxf(ss * inv_n - m * m, 0.f);
    float a = gamma[t] * rsqrtf(var + BN_EPS);
    cA[t] = a;
    cC[t] = beta[t] - m * a;
  }
}

// y = act(in) @ W + bias ; accumulate column sum/sumsq of y into outStats.
// act(v) = relu(aA[k]*v + aC[k]) computed from actStats (ACT=1) else identity.
// Block: 512 threads, 128 rows per block. W: [128][128] row-major.
template <int ACT>
__global__ __launch_bounds__(512, 4)
void k_gemm(const float* __restrict__ in, float* __restrict__ out,
            const float* __restrict__ W, const float* __restrict__ bias,
            const float* __restrict__ actStats, const float* __restrict__ actG,
            const float* __restrict__ actB, float act_inv_n,
            float* __restrict__ outStats) {
  __shared__ float Wl[HDIM * HDIM];
  __shared__ float sred[2 * HDIM];
  __shared__ float aA[HDIM], aC[HDIM];
  const int t = threadIdx.x;

  const float4* Wg = (const float4*)W;
  float4* Wl4 = (float4*)Wl;
  #pragma unroll 4
  for (int u = t; u < HDIM * HDIM / 4; u += 512) Wl4[u] = Wg[u];
  if (t < 2 * HDIM) sred[t] = 0.f;
  if (ACT) bn_coefs(actStats, actG, actB, act_inv_n, aA, aC, t);
  __syncthreads();

  const int q  = t & 7;     // channel group: c = q*4 + 32*j + comp
  const int rg = t >> 3;    // 0..63 row group (2 rows each)
  const size_t row0 = (size_t)blockIdx.x * 128 + (size_t)rg * 2;
  const float* x0 = in + row0 * HDIM;
  const float* x1 = x0 + HDIM;

  float4 acc0[4], acc1[4];
  #pragma unroll
  for (int j = 0; j < 4; ++j) {
    acc0[j] = make_float4(0.f, 0.f, 0.f, 0.f);
    acc1[j] = make_float4(0.f, 0.f, 0.f, 0.f);
  }

  for (int k = 0; k < HDIM; k += 4) {
    float4 xa = *(const float4*)(x0 + k);
    float4 xb = *(const float4*)(x1 + k);
    if (ACT) {
      xa.x = fmaxf(fmaf(aA[k + 0], xa.x, aC[k + 0]), 0.f);
      xa.y = fmaxf(fmaf(aA[k + 1], xa.y, aC[k + 1]), 0.f);
      xa.z = fmaxf(fmaf(aA[k + 2], xa.z, aC[k + 2]), 0.f);
      xa.w = fmaxf(fmaf(aA[k + 3], xa.w, aC[k + 3]), 0.f);
      xb.x = fmaxf(fmaf(aA[k + 0], xb.x, aC[k + 0]), 0.f);
      xb.y = fmaxf(fmaf(aA[k + 1], xb.y, aC[k + 1]), 0.f);
      xb.z = fmaxf(fmaf(aA[k + 2], xb.z, aC[k + 2]), 0.f);
      xb.w = fmaxf(fmaf(aA[k + 3], xb.w, aC[k + 3]), 0.f);
    }
    #pragma unroll
    for (int j = 0; j < 4; ++j) {
      float4 w0 = Wl4[(k + 0) * 32 + q + 8 * j];
      float4 w1 = Wl4[(k + 1) * 32 + q + 8 * j];
      float4 w2 = Wl4[(k + 2) * 32 + q + 8 * j];
      float4 w3 = Wl4[(k + 3) * 32 + q + 8 * j];
      acc0[j].x += xa.x * w0.x + xa.y * w1.x + xa.z * w2.x + xa.w * w3.x;
      acc0[j].y += xa.x * w0.y + xa.y * w1.y + xa.z * w2.y + xa.w * w3.y;
      acc0[j].z += xa.x * w0.z + xa.y * w1.z + xa.z * w2.z + xa.w * w3.z;
      acc0[j].w += xa.x * w0.w + xa.y * w1.w + xa.z * w2.w + xa.w * w3.w;
      acc1[j].x += xb.x * w0.x + xb.y * w1.x + xb.z * w2.x + xb.w * w3.x;
      acc1[j].y += xb.x * w0.y + xb.y * w1.y + xb.z * w2.y + xb.w * w3.y;
      acc1[j].z += xb.x * w0.z + xb.y * w1.z + xb.z * w2.z + xb.w * w3.z;
      acc1[j].w += xb.x * w0.w + xb.y * w1.w + xb.z * w2.w + xb.w * w3.w;
    }
  }

  float* o0 = out + row0 * HDIM;
  float* o1 = o0 + HDIM;
  #pragma unroll
  for (int j = 0; j < 4; ++j) {
    const int cbase = q * 4 + 32 * j;
    float4 b4 = *(const float4*)(bias + cbase);
    float4 y0, y1;
    y0.x = acc0[j].x + b4.x; y0.y = acc0[j].y + b4.y;
    y0.z = acc0[j].z + b4.z; y0.w = acc0[j].w + b4.w;
    y1.x = acc1[j].x + b4.x; y1.y = acc1[j].y + b4.y;
    y1.z = acc1[j].z + b4.z; y1.w = acc1[j].w + b4.w;
    *(float4*)(o0 + cbase) = y0;
    *(float4*)(o1 + cbase) = y1;
    // column stats (sum, sumsq) over the block's 128 rows
    float s0 = wred_sum(y0.x + y1.x), q0 = wred_sum(y0.x * y0.x + y1.x * y1.x);
    float s1 = wred_sum(y0.y + y1.y), q1 = wred_sum(y0.y * y0.y + y1.y * y1.y);
    float s2 = wred_sum(y0.z + y1.z), q2 = wred_sum(y0.z * y0.z + y1.z * y1.z);
    float s3 = wred_sum(y0.w + y1.w), q3 = wred_sum(y0.w * y0.w + y1.w * y1.w);
    if ((t & 56) == 0) {  // one lane per q per wave
      atomicAdd(&sred[cbase + 0], s0); atomicAdd(&sred[HDIM + cbase + 0], q0);
      atomicAdd(&sred[cbase + 1], s1); atomicAdd(&sred[HDIM + cbase + 1], q1);
      atomicAdd(&sred[cbase + 2], s2); atomicAdd(&sred[HDIM + cbase + 2], q2);
      atomicAdd(&sred[cbase + 3], s3); atomicAdd(&sred[HDIM + cbase + 3], q3);
    }
  }
  __syncthreads();
  if (t < 2 * HDIM) atomicAdd(&outStats[t], sred[t]);
}

// Per-graph GIN aggregation: h = act(x) + sum_{e: dst==d} act(x[src]).
// One block per graph; node features staged in LDS; per-dst CSR built in LDS.
// Latency fixes vs R1: float4 channel packing (4x fewer LDS issues), 4x edge
// unroll (4 independent ds_read_b128 in flight), edge list read once into
// registers, wave-parallel prefix scan, NPG-templated static LDS so layers
// 1/2 get 3-6 blocks/CU instead of 2.
template <int NPG>
__global__ __launch_bounds__(512, 2)
void k_agg(const float* __restrict__ xin_g, float* __restrict__ hout,
           const int* __restrict__ esrc, const int* __restrict__ edst,
           int shift,
           const float* __restrict__ actStats, const float* __restrict__ actG,
           const float* __restrict__ actB, float act_inv_n) {
  __shared__ float xs[NPG * HDIM];
  __shared__ int   srcs[EPG];
  __shared__ int   cnt[NPG], off[NPG], cur[NPG], scn[NPG];
  __shared__ float aA[HDIM], aC[HDIM];
  const int t = threadIdx.x;
  const int g = blockIdx.x;
  const bool act = (actStats != nullptr);

  // read this graph's edge block once (coalesced), keep in registers
  int myd[4], mys[4];
  const int ebase = g * EPG;
  #pragma unroll
  for (int u = 0; u < 4; ++u) {
    const int e = ebase + t + u * 512;
    myd[u] = (edst[e] >> shift) - g * NPG;
    mys[u] = (esrc[e] >> shift) - g * NPG;
  }

  if (act) bn_coefs(actStats, actG, actB, act_inv_n, aA, aC, t);
  if (t < NPG) { cnt[t] = 0; cur[t] = 0; }
  __syncthreads();

  // stage activated node features + count in-degree
  const float4* xg = (const float4*)(xin_g + (size_t)g * NPG * HDIM);
  float4* xs4 = (float4*)xs;
  for (int u = t; u < NPG * (HDIM / 4); u += 512) {
    float4 v = xg[u];
    if (act) {
      int c = (u & 31) * 4;
      v.x = fmaxf(fmaf(aA[c + 0], v.x, aC[c + 0]), 0.f);
      v.y = fmaxf(fmaf(aA[c + 1], v.y, aC[c + 1]), 0.f);
      v.z = fmaxf(fmaf(aA[c + 2], v.z, aC[c + 2]), 0.f);
      v.w = fmaxf(fmaf(aA[c + 3], v.w, aC[c + 3]), 0.f);
    }
    xs4[u] = v;
  }
  #pragma unroll
  for (int u = 0; u < 4; ++u) atomicAdd(&cnt[myd[u]], 1);
  __syncthreads();

  // exclusive prefix scan of cnt -> off (Hillis-Steele, NPG <= 128)
  if (t < NPG) scn[t] = cnt[t];
  __syncthreads();
  #pragma unroll
  for (int s = 1; s < NPG; s <<= 1) {
    int v = (t < NPG && t >= s) ? scn[t - s] : 0;
    __syncthreads();
    if (t < NPG) scn[t] += v;
    __syncthreads();
  }
  if (t < NPG) off[t] = scn[t] - cnt[t];
  __syncthreads();

  // scatter src ids grouped by dst
  #pragma unroll
  for (int u = 0; u < 4; ++u) {
    int p = off[myd[u]] + atomicAdd(&cur[myd[u]], 1);
    srcs[p] = mys[u];
  }
  __syncthreads();

  // aggregate: lane owns 4 consecutive channels (float4) of one dst;
  // 4x edge unroll keeps 4 independent b128 LDS reads in flight.
  const int c4 = t & 31;    // float4 channel group
  const int dg = t >> 5;    // 0..15 dst group
  float4* hb4 = (float4*)(hout + (size_t)g * NPG * HDIM);
  for (int d = dg; d < NPG; d += 16) {
    float4 acc = xs4[d * 32 + c4];
    int e = off[d];
    const int e2 = e + cnt[d];
    for (; e + 4 <= e2; e += 4) {
      const int s0 = srcs[e], s1 = srcs[e + 1], s2 = srcs[e + 2], s3 = srcs[e + 3];
      float4 v0 = xs4[s0 * 32 + c4];
      float4 v1 = xs4[s1 * 32 + c4];
      float4 v2 = xs4[s2 * 32 + c4];
      float4 v3 = xs4[s3 * 32 + c4];
      acc.x += (v0.x + v1.x) + (v2.x + v3.x);
      acc.y += (v0.y + v1.y) + (v2.y + v3.y);
      acc.z += (v0.z + v1.z) + (v2.z + v3.z);
      acc.w += (v0.w + v1.w) + (v2.w + v3.w);
    }
    for (; e < e2; ++e) {
      float4 v = xs4[srcs[e] * 32 + c4];
      acc.x += v.x; acc.y += v.y; acc.z += v.z; acc.w += v.w;
    }
    hb4[d * 32 + c4] = acc;
  }
}

// x' = pairwise-haar(act(h)) ; emb[g] = per-graph sum of x' ; embd col-stats.
__global__ __launch_bounds__(256, 4)
void k_pool(const float* __restrict__ hin, float* __restrict__ xout,
            float* __restrict__ emb, int layer, int npg_in,
            const float* __restrict__ actStats, const float* __restrict__ actG,
            const float* __restrict__ actB, float act_inv_n,
            float* __restrict__ embStats) {
  __shared__ float aA[HDIM], aC[HDIM];
  __shared__ float red[256];
  const int t = threadIdx.x;
  const int g = blockIdx.x;
  bn_coefs(actStats, actG, actB, act_inv_n, aA, aC, t);
  __syncthreads();
  const int c = t & 127;
  const int ph = t >> 7;
  const int npg_out = npg_in >> 1;
  const float* hb = hin + (size_t)g * npg_in * HDIM;
  float* xb = xout + (size_t)g * npg_out * HDIM;
  const float a = aA[c], cc = aC[c];
  float es = 0.f;
  for (int p = ph; p < npg_out; p += 2) {
    float v0 = fmaxf(fmaf(a, hb[(2 * p    ) * HDIM + c], cc), 0.f);
    float v1 = fmaxf(fmaf(a, hb[(2 * p + 1) * HDIM + c], cc), 0.f);
    float xv = (v0 + v1) * INV_SQRT2;
    xb[p * HDIM + c] = xv;
    es += xv;
  }
  red[t] = es;
  __syncthreads();
  if (t < HDIM) {
    float e = red[t] + red[t + HDIM];
    emb[(size_t)g * 384 + layer * HDIM + t] = e;
    atomicAdd(&embStats[t], e);
    atomicAdd(&embStats[HDIM + t], e * e);
  }
}

// out[g] = relu(bne(emb[g])) @ lin_w + lin_b
__global__ __launch_bounds__(128, 8)
void k_final(const float* __restrict__ emb,
             const float* __restrict__ se0, const float* __restrict__ se1,
             const float* __restrict__ se2,
             const float* __restrict__ bneG, const float* __restrict__ bneB,
             const float* __restrict__ linW, const float* __restrict__ linB,
             float* __restrict__ outp) {
  __shared__ float ev[384];
  __shared__ float eA[384], eC[384];
  const int t = threadIdx.x;
  const int g = blockIdx.x;
  if (t < 128) {
    const float* se[3] = {se0, se1, se2};
    const float inv_n = 1.f / (float)G_GRAPHS;
    #pragma unroll
    for (int l = 0; l < 3; ++l) {
      float s  = se[l][t];
      float ss = se[l][128 + t];
      float m  = s * inv_n;
      float var = fmaxf(ss * inv_n - m * m, 0.f);
      float a = bneG[l * 128 + t] * rsqrtf(var + BN_EPS);
      eA[l * 128 + t] = a;
      eC[l * 128 + t] = bneB[l * 128 + t] - m * a;
    }
  }
  __syncthreads();
  for (int j = t; j < 384; j += 128)
    ev[j] = fmaxf(fmaf(eA[j], emb[(size_t)g * 384 + j], eC[j]), 0.f);
  __syncthreads();
  if (t < 10) {
    float acc = linB[t];
    #pragma unroll 8
    for (int j = 0; j < 384; ++j) acc += ev[j] * linW[j * 10 + t];
    outp[g * 10 + t] = acc;
  }
}

extern "C" void kernel_launch(void* const* d_in, const int* in_sizes, int n_in,
                              void* d_out, int out_size, void* d_ws, size_t ws_size,
                              hipStream_t stream) {
  const float* x           = (const float*)d_in[0];
  const int*   ei          = (const int*)  d_in[1];
  const float* lin_start_w = (const float*)d_in[2];
  const float* lin_start_b = (const float*)d_in[3];
  const float* bn_start_g  = (const float*)d_in[4];
  const float* bn_start_b  = (const float*)d_in[5];
  const float* conv_w1     = (const float*)d_in[6];
  const float* conv_b1     = (const float*)d_in[7];
  const float* conv_bn_g   = (const float*)d_in[8];
  const float* conv_bn_b   = (const float*)d_in[9];
  const float* conv_w2     = (const float*)d_in[10];
  const float* conv_b2     = (const float*)d_in[11];
  const float* bn_g        = (const float*)d_in[12];
  const float* bn_b        = (const float*)d_in[13];
  const float* bne_g       = (const float*)d_in[14];
  const float* bne_b       = (const float*)d_in[15];
  const float* lin_w       = (const float*)d_in[16];
  const float* lin_b       = (const float*)d_in[17];
  float* outp = (float*)d_out;

  float* ws = (float*)d_ws;
  const size_t NH = (size_t)N_NODES * HDIM;
  float* buf0  = ws;
  float* buf1  = ws + NH;
  float* emb   = ws + 2 * NH;                     // G * 384
  float* stats = emb + (size_t)G_GRAPHS * 384;    // 10 slots * 256 floats
  // slots: 0: bn_start; per layer i: 1+3i: conv_bn, 2+3i: bn, 3+3i: bne

  hipMemsetAsync(stats, 0, 10 * 256 * sizeof(float), stream);

  const int* esrc = ei;
  const int* edst = ei + E_EDGES;

  // stage A: y0 = x @ lin_start_w + b  (stats -> slot 0)
  k_gemm<0><<<N_NODES / 128, 512, 0, stream>>>(
      x, buf0, lin_start_w, lin_start_b, nullptr, nullptr, nullptr, 0.f, stats);

  for (int i = 0; i < 3; ++i) {
    const int n   = N_NODES >> i;
    const float inv_n = 1.f / (float)n;
    float* s1 = stats + (1 + 3 * i) * 256;
    float* s2 = stats + (2 + 3 * i) * 256;
    float* se = stats + (3 + 3 * i) * 256;

    // h = act(x) + aggregate(act(x))  (act only at layer 0: bn_start+relu)
    const float* aS = (i == 0) ? stats : nullptr;
    if (i == 0)
      k_agg<128><<<G_GRAPHS, 512, 0, stream>>>(buf0, buf1, esrc, edst, 0,
          aS, bn_start_g, bn_start_b, 1.f / (float)N_NODES);
    else if (i == 1)
      k_agg<64><<<G_GRAPHS, 512, 0, stream>>>(buf0, buf1, esrc, edst, 1,
          aS, bn_start_g, bn_start_b, 1.f / (float)N_NODES);
    else
      k_agg<32><<<G_GRAPHS, 512, 0, stream>>>(buf0, buf1, esrc, edst, 2,
          aS, bn_start_g, bn_start_b, 1.f / (float)N_NODES);

    // h1 = h @ w1 + b1 (stats -> s1)
    k_gemm<0><<<n / 128, 512, 0, stream>>>(
        buf1, buf0, conv_w1 + (size_t)i * HDIM * HDIM, conv_b1 + i * HDIM,
        nullptr, nullptr, nullptr, 0.f, s1);
    // h2 = relu(bn(h1)) @ w2 + b2 (stats -> s2)
    k_gemm<1><<<n / 128, 512, 0, stream>>>(
        buf0, buf1, conv_w2 + (size_t)i * HDIM * HDIM, conv_b2 + i * HDIM,
        s1, conv_bn_g + i * HDIM, conv_bn_b + i * HDIM, inv_n, s2);
    // x' = haar(relu(bn(h2))) ; emb col i ; embd stats -> se
    k_pool<<<G_GRAPHS, 256, 0, stream>>>(
        buf1, buf0, emb, i, NPG0 >> i,
        s2, bn_g + i * HDIM, bn_b + i * HDIM, inv_n, se);
  }

  k_final<<<G_GRAPHS, 128, 0, stream>>>(
      emb, stats + 3 * 256, stats + 6 * 256, stats + 9 * 256,
      bne_g, bne_b, lin_w, lin_b, outp);
}

// Round 3
// 399.547 us; speedup vs baseline: 2.3052x; 1.5089x over previous
//
#include <hip/hip_runtime.h>

#define N_NODES  131072
#define G_GRAPHS 1024
#define NPG0     128
#define HDIM     128
#define E_EDGES  2097152
#define EPG      2048
#define BN_EPS   1e-5f
#define INV_SQRT2 0.70710678118654752440f

typedef __attribute__((ext_vector_type(8))) short bf16x8;
typedef __attribute__((ext_vector_type(4))) float f32x4;

__device__ __forceinline__ float bf2f(ushort u) {
  union { unsigned int i; float f; } v; v.i = ((unsigned int)u) << 16; return v.f;
}
__device__ __forceinline__ ushort f2bf(float f) {
  union { float f; unsigned int i; } v; v.f = f;
  unsigned int u = v.i;
  return (ushort)((u + 0x7FFFu + ((u >> 16) & 1u)) >> 16);
}
__device__ __forceinline__ float redgrp(float v) {
  v += __shfl_xor(v, 16); v += __shfl_xor(v, 32); return v;
}

// BN scale/shift coefs from raw (sum,sumsq) stats. t<128 participates.
__device__ __forceinline__ void bn_coefs(const float* __restrict__ stats,
                                         const float* __restrict__ gamma,
                                         const float* __restrict__ beta,
                                         float inv_n, float* cA, float* cC, int t) {
  if (t < HDIM) {
    float s  = stats[t];
    float ss = stats[HDIM + t];
    float m  = s * inv_n;
    float var = fmaxf(ss * inv_n - m * m, 0.f);
    float a = gamma[t] * rsqrtf(var + BN_EPS);
    cA[t] = a;
    cC[t] = beta[t] - m * a;
  }
}

// Transpose + bf16-convert the 7 weight matrices into wt[m][n][k].
__global__ __launch_bounds__(256, 2)
void k_prep(const float* __restrict__ w_lin_start, const float* __restrict__ w_conv1,
            const float* __restrict__ w_conv2, ushort* __restrict__ wt) {
  __shared__ ushort T[128 * 136];
  const int m = blockIdx.x;      // 0: lin_start, 1..3: conv_w1, 4..6: conv_w2
  const int t = threadIdx.x;
  const float* W = (m == 0) ? w_lin_start
                 : (m <= 3) ? w_conv1 + (size_t)(m - 1) * HDIM * HDIM
                            : w_conv2 + (size_t)(m - 4) * HDIM * HDIM;
  for (int it = 0; it < 64; ++it) {
    int idx = it * 256 + t;          // W row-major [k][n]
    int k = idx >> 7, n = idx & 127;
    T[k * 136 + n] = f2bf(W[idx]);
  }
  __syncthreads();
  ushort* o = wt + (size_t)m * HDIM * HDIM;  // [n][k]
  for (int it = 0; it < 64; ++it) {
    int idx = it * 256 + t;
    int n = idx >> 7, k = idx & 127;
    o[idx] = T[k * 136 + n];
  }
}

// out[n x 128] = (act(in) @ W) + bias via bf16 MFMA; col sum/sumsq -> outStats.
// Block: 256 thr = 4 waves, 128 rows; wave = 32 rows x 128 cols.
// Wt LDS layout [kblk][col][16B], kblk stride 1032 ushorts (pad) -> both the
// b128 staging writes and the B-frag reads are bank-conflict-free.
template <int ACT, int FP32IN>
__global__ __launch_bounds__(256, 3)
void k_mm(const void* __restrict__ in_v, ushort* __restrict__ out,
          const ushort* __restrict__ Wt, const float* __restrict__ bias,
          const float* __restrict__ actStats, const float* __restrict__ actG,
          const float* __restrict__ actB, float act_inv_n,
          float* __restrict__ outStats) {
  __shared__ ushort WtL[16 * 1032];
  __shared__ float biasL[HDIM];
  __shared__ float sred[2 * HDIM];
  __shared__ float aA[HDIM], aC[HDIM];
  const int t = threadIdx.x;
  const int lane = t & 63;
  const int w = t >> 6;
  const int lr = lane & 15;
  const int lg = lane >> 4;

  // stage Wt -> LDS (b128, conflict-free)
  #pragma unroll
  for (int i = 0; i < 8; ++i) {
    int chunk = i * 256 + t;            // 2048 chunks of 8 ushort
    int n = chunk >> 4, kb = chunk & 15;
    *(bf16x8*)&WtL[kb * 1032 + n * 8] = *(const bf16x8*)&Wt[chunk * 8];
  }
  if (t < HDIM) biasL[t] = bias[t];
  if (t < 2 * HDIM) sred[t] = 0.f;
  if (ACT) bn_coefs(actStats, actG, actB, act_inv_n, aA, aC, t);
  __syncthreads();

  const int r0 = blockIdx.x * 128 + w * 32;
  const float*  inF = (const float*)in_v;
  const ushort* inB = (const ushort*)in_v;

  f32x4 acc[2][8];
  #pragma unroll
  for (int i = 0; i < 2; ++i)
    #pragma unroll
    for (int cf = 0; cf < 8; ++cf)
      acc[i][cf] = (f32x4){0.f, 0.f, 0.f, 0.f};

  #pragma unroll
  for (int ks = 0; ks < 4; ++ks) {
    const int k0 = ks * 32 + lg * 8;
    bf16x8 afr[2];
    #pragma unroll
    for (int i = 0; i < 2; ++i) {
      const int row = r0 + i * 16 + lr;
      if (FP32IN) {
        const float* ap = inF + (size_t)row * HDIM + k0;
        float4 v0 = *(const float4*)ap;
        float4 v1 = *(const float4*)(ap + 4);
        afr[i][0] = (short)f2bf(v0.x); afr[i][1] = (short)f2bf(v0.y);
        afr[i][2] = (short)f2bf(v0.z); afr[i][3] = (short)f2bf(v0.w);
        afr[i][4] = (short)f2bf(v1.x); afr[i][5] = (short)f2bf(v1.y);
        afr[i][6] = (short)f2bf(v1.z); afr[i][7] = (short)f2bf(v1.w);
      } else {
        bf16x8 a = *(const bf16x8*)(inB + (size_t)row * HDIM + k0);
        if (ACT) {
          #pragma unroll
          for (int j = 0; j < 8; ++j) {
            float f = fmaxf(fmaf(aA[k0 + j], bf2f((ushort)a[j]), aC[k0 + j]), 0.f);
            a[j] = (short)f2bf(f);
          }
        }
        afr[i] = a;
      }
    }
    const int kb = ks * 4 + lg;
    #pragma unroll
    for (int cf = 0; cf < 8; ++cf) {
      bf16x8 b = *(const bf16x8*)&WtL[kb * 1032 + (cf * 16 + lr) * 8];
      acc[0][cf] = __builtin_amdgcn_mfma_f32_16x16x32_bf16(afr[0], b, acc[0][cf], 0, 0, 0);
      acc[1][cf] = __builtin_amdgcn_mfma_f32_16x16x32_bf16(afr[1], b, acc[1][cf], 0, 0, 0);
    }
  }

  // epilogue: bias, store bf16, column stats (D layout: col=lane&15, row=lg*4+r)
  #pragma unroll
  for (int cf = 0; cf < 8; ++cf) {
    const int col = cf * 16 + lr;
    const float bia = biasL[col];
    float s = 0.f, qq = 0.f;
    #pragma unroll
    for (int i = 0; i < 2; ++i) {
      const int rowb = r0 + i * 16 + lg * 4;
      #pragma unroll
      for (int r = 0; r < 4; ++r) {
        float y = acc[i][cf][r] + bia;
        out[(size_t)(rowb + r) * HDIM + col] = f2bf(y);
        s += y; qq += y * y;
      }
    }
    s = redgrp(s); qq = redgrp(qq);
    if (lg == 0) { atomicAdd(&sred[col], s); atomicAdd(&sred[HDIM + col], qq); }
  }
  __syncthreads();
  if (t < 2 * HDIM) atomicAdd(&outStats[t], sred[t]);
}

// Per-graph GIN aggregation on bf16 node features (f32 LDS internally).
template <int NPG>
__global__ __launch_bounds__(512, 2)
void k_agg(const ushort* __restrict__ xin_g, ushort* __restrict__ hout,
           const int* __restrict__ esrc, const int* __restrict__ edst,
           int shift,
           const float* __restrict__ actStats, const float* __restrict__ actG,
           const float* __restrict__ actB, float act_inv_n) {
  __shared__ float xs[NPG * HDIM];
  __shared__ int   srcs[EPG];
  __shared__ int   cnt[NPG], off[NPG], cur[NPG], scn[NPG];
  __shared__ float aA[HDIM], aC[HDIM];
  const int t = threadIdx.x;
  const int g = blockIdx.x;
  const bool act = (actStats != nullptr);

  int myd[4], mys[4];
  const int ebase = g * EPG;
  #pragma unroll
  for (int u = 0; u < 4; ++u) {
    const int e = ebase + t + u * 512;
    myd[u] = (edst[e] >> shift) - g * NPG;
    mys[u] = (esrc[e] >> shift) - g * NPG;
  }

  if (act) bn_coefs(actStats, actG, actB, act_inv_n, aA, aC, t);
  if (t < NPG) { cnt[t] = 0; cur[t] = 0; }
  __syncthreads();

  // stage (bf16 -> f32, act for layer 0)
  const ushort* xg = xin_g + (size_t)g * NPG * HDIM;
  float4* xs4 = (float4*)xs;
  for (int u = t; u < NPG * 16; u += 512) {
    bf16x8 v = *(const bf16x8*)(xg + u * 8);
    const int c0 = (u & 15) * 8;
    float f[8];
    #pragma unroll
    for (int j = 0; j < 8; ++j) {
      f[j] = bf2f((ushort)v[j]);
      if (act) f[j] = fmaxf(fmaf(aA[c0 + j], f[j], aC[c0 + j]), 0.f);
    }
    xs4[u * 2 + 0] = make_float4(f[0], f[1], f[2], f[3]);
    xs4[u * 2 + 1] = make_float4(f[4], f[5], f[6], f[7]);
  }
  #pragma unroll
  for (int u = 0; u < 4; ++u) atomicAdd(&cnt[myd[u]], 1);
  __syncthreads();

  if (t < NPG) scn[t] = cnt[t];
  __syncthreads();
  #pragma unroll
  for (int s = 1; s < NPG; s <<= 1) {
    int v = (t < NPG && t >= s) ? scn[t - s] : 0;
    __syncthreads();
    if (t < NPG) scn[t] += v;
    __syncthreads();
  }
  if (t < NPG) off[t] = scn[t] - cnt[t];
  __syncthreads();

  #pragma unroll
  for (int u = 0; u < 4; ++u) {
    int p = off[myd[u]] + atomicAdd(&cur[myd[u]], 1);
    srcs[p] = mys[u];
  }
  __syncthreads();

  const int c4 = t & 31;
  const int dg = t >> 5;
  ushort* hb = hout + (size_t)g * NPG * HDIM;
  for (int d = dg; d < NPG; d += 16) {
    float4 acc = xs4[d * 32 + c4];
    int e = off[d];
    const int e2 = e + cnt[d];
    for (; e + 4 <= e2; e += 4) {
      const int s0 = srcs[e], s1 = srcs[e + 1], s2 = srcs[e + 2], s3 = srcs[e + 3];
      float4 v0 = xs4[s0 * 32 + c4];
      float4 v1 = xs4[s1 * 32 + c4];
      float4 v2 = xs4[s2 * 32 + c4];
      float4 v3 = xs4[s3 * 32 + c4];
      acc.x += (v0.x + v1.x) + (v2.x + v3.x);
      acc.y += (v0.y + v1.y) + (v2.y + v3.y);
      acc.z += (v0.z + v1.z) + (v2.z + v3.z);
      acc.w += (v0.w + v1.w) + (v2.w + v3.w);
    }
    for (; e < e2; ++e) {
      float4 v = xs4[srcs[e] * 32 + c4];
      acc.x += v.x; acc.y += v.y; acc.z += v.z; acc.w += v.w;
    }
    ushort4 hv;
    hv.x = f2bf(acc.x); hv.y = f2bf(acc.y); hv.z = f2bf(acc.z); hv.w = f2bf(acc.w);
    *(ushort4*)&hb[d * HDIM + c4 * 4] = hv;
  }
}

// x' = haar(act(h)) ; emb[g] ; embd col-stats. bf16 in/out, emb f32.
__global__ __launch_bounds__(256, 4)
void k_pool(const ushort* __restrict__ hin, ushort* __restrict__ xout,
            float* __restrict__ emb, int layer, int npg_in,
            const float* __restrict__ actStats, const float* __restrict__ actG,
            const float* __restrict__ actB, float act_inv_n,
            float* __restrict__ embStats) {
  __shared__ float aA[HDIM], aC[HDIM];
  __shared__ float red[256];
  const int t = threadIdx.x;
  const int g = blockIdx.x;
  bn_coefs(actStats, actG, actB, act_inv_n, aA, aC, t);
  __syncthreads();
  const int c = t & 127;
  const int ph = t >> 7;
  const int npg_out = npg_in >> 1;
  const ushort* hb = hin + (size_t)g * npg_in * HDIM;
  ushort* xb = xout + (size_t)g * npg_out * HDIM;
  const float a = aA[c], cc = aC[c];
  float es = 0.f;
  for (int p = ph; p < npg_out; p += 2) {
    float v0 = fmaxf(fmaf(a, bf2f(hb[(2 * p    ) * HDIM + c]), cc), 0.f);
    float v1 = fmaxf(fmaf(a, bf2f(hb[(2 * p + 1) * HDIM + c]), cc), 0.f);
    float xv = (v0 + v1) * INV_SQRT2;
    xb[p * HDIM + c] = f2bf(xv);
    es += xv;
  }
  red[t] = es;
  __syncthreads();
  if (t < HDIM) {
    float e = red[t] + red[t + HDIM];
    emb[(size_t)g * 384 + layer * HDIM + t] = e;
    atomicAdd(&embStats[t], e);
    atomicAdd(&embStats[HDIM + t], e * e);
  }
}

__global__ __launch_bounds__(128, 8)
void k_final(const float* __restrict__ emb,
             const float* __restrict__ se0, const float* __restrict__ se1,
             const float* __restrict__ se2,
             const float* __restrict__ bneG, const float* __restrict__ bneB,
             const float* __restrict__ linW, const float* __restrict__ linB,
             float* __restrict__ outp) {
  __shared__ float ev[384];
  __shared__ float eA[384], eC[384];
  const int t = threadIdx.x;
  const int g = blockIdx.x;
  if (t < 128) {
    const float* se[3] = {se0, se1, se2};
    const float inv_n = 1.f / (float)G_GRAPHS;
    #pragma unroll
    for (int l = 0; l < 3; ++l) {
      float s  = se[l][t];
      float ss = se[l][128 + t];
      float m  = s * inv_n;
      float var = fmaxf(ss * inv_n - m * m, 0.f);
      float a = bneG[l * 128 + t] * rsqrtf(var + BN_EPS);
      eA[l * 128 + t] = a;
      eC[l * 128 + t] = bneB[l * 128 + t] - m * a;
    }
  }
  __syncthreads();
  for (int j = t; j < 384; j += 128)
    ev[j] = fmaxf(fmaf(eA[j], emb[(size_t)g * 384 + j], eC[j]), 0.f);
  __syncthreads();
  if (t < 10) {
    float acc = linB[t];
    #pragma unroll 8
    for (int j = 0; j < 384; ++j) acc += ev[j] * linW[j * 10 + t];
    outp[g * 10 + t] = acc;
  }
}

extern "C" void kernel_launch(void* const* d_in, const int* in_sizes, int n_in,
                              void* d_out, int out_size, void* d_ws, size_t ws_size,
                              hipStream_t stream) {
  const float* x           = (const float*)d_in[0];
  const int*   ei          = (const int*)  d_in[1];
  const float* lin_start_w = (const float*)d_in[2];
  const float* lin_start_b = (const float*)d_in[3];
  const float* bn_start_g  = (const float*)d_in[4];
  const float* bn_start_b  = (const float*)d_in[5];
  const float* conv_w1     = (const float*)d_in[6];
  const float* conv_b1     = (const float*)d_in[7];
  const float* conv_bn_g   = (const float*)d_in[8];
  const float* conv_bn_b   = (const float*)d_in[9];
  const float* conv_w2     = (const float*)d_in[10];
  const float* conv_b2     = (const float*)d_in[11];
  const float* bn_g        = (const float*)d_in[12];
  const float* bn_b        = (const float*)d_in[13];
  const float* bne_g       = (const float*)d_in[14];
  const float* bne_b       = (const float*)d_in[15];
  const float* lin_w       = (const float*)d_in[16];
  const float* lin_b       = (const float*)d_in[17];
  float* outp = (float*)d_out;

  const size_t NH = (size_t)N_NODES * HDIM;
  float*  stats = (float*)d_ws;                       // 10 slots * 256
  float*  emb   = stats + 10 * 256;                   // G * 384
  ushort* wt    = (ushort*)(emb + (size_t)G_GRAPHS * 384);  // 7 * 128 * 128
  ushort* buf0  = wt + 7 * HDIM * HDIM;
  ushort* buf1  = buf0 + NH;

  hipMemsetAsync(stats, 0, 10 * 256 * sizeof(float), stream);

  const int* esrc = ei;
  const int* edst = ei + E_EDGES;

  k_prep<<<7, 256, 0, stream>>>(lin_start_w, conv_w1, conv_w2, wt);

  // y0 = x @ lin_start_w + b (stats -> slot 0)
  k_mm<0, 1><<<N_NODES / 128, 256, 0, stream>>>(
      x, buf0, wt, lin_start_b, nullptr, nullptr, nullptr, 0.f, stats);

  for (int i = 0; i < 3; ++i) {
    const int n = N_NODES >> i;
    const float inv_n = 1.f / (float)n;
    float* s1 = stats + (1 + 3 * i) * 256;
    float* s2 = stats + (2 + 3 * i) * 256;
    float* se = stats + (3 + 3 * i) * 256;
    const ushort* wt1 = wt + (size_t)(1 + i) * HDIM * HDIM;
    const ushort* wt2 = wt + (size_t)(4 + i) * HDIM * HDIM;

    const float* aS = (i == 0) ? stats : nullptr;
    if (i == 0)
      k_agg<128><<<G_GRAPHS, 512, 0, stream>>>(buf0, buf1, esrc, edst, 0,
          aS, bn_start_g, bn_start_b, 1.f / (float)N_NODES);
    else if (i == 1)
      k_agg<64><<<G_GRAPHS, 512, 0, stream>>>(buf0, buf1, esrc, edst, 1,
          aS, bn_start_g, bn_start_b, 1.f / (float)N_NODES);
    else
      k_agg<32><<<G_GRAPHS, 512, 0, stream>>>(buf0, buf1, esrc, edst, 2,
          aS, bn_start_g, bn_start_b, 1.f / (float)N_NODES);

    // h1 = h @ w1 + b1 (stats -> s1)
    k_mm<0, 0><<<n / 128, 256, 0, stream>>>(
        buf1, buf0, wt1, conv_b1 + i * HDIM, nullptr, nullptr, nullptr, 0.f, s1);
    // h2 = relu(bn(h1)) @ w2 + b2 (stats -> s2)
    k_mm<1, 0><<<n / 128, 256, 0, stream>>>(
        buf0, buf1, wt2, conv_b2 + i * HDIM,
        s1, conv_bn_g + i * HDIM, conv_bn_b + i * HDIM, inv_n, s2);
    // x' = haar(relu(bn(h2))) ; emb col i ; embd stats -> se
    k_pool<<<G_GRAPHS, 256, 0, stream>>>(
        buf1, buf0, emb, i, NPG0 >> i,
        s2, bn_g + i * HDIM, bn_b + i * HDIM, inv_n, se);
  }

  k_final<<<G_GRAPHS, 128, 0, stream>>>(
      emb, stats + 3 * 256, stats + 6 * 256, stats + 9 * 256,
      bne_g, bne_b, lin_w, lin_b, outp);
}

// Round 4
// 398.182 us; speedup vs baseline: 2.3131x; 1.0034x over previous
//
#include <hip/hip_runtime.h>

#define N_NODES  131072
#define G_GRAPHS 1024
#define NPG0     128
#define HDIM     128
#define E_EDGES  2097152
#define EPG      2048
#define BN_EPS   1e-5f
#define INV_SQRT2 0.70710678118654752440f

typedef __attribute__((ext_vector_type(8))) short bf16x8;
typedef __attribute__((ext_vector_type(4))) float f32x4;

__device__ __forceinline__ float bf2f(ushort u) {
  union { unsigned int i; float f; } v; v.i = ((unsigned int)u) << 16; return v.f;
}
__device__ __forceinline__ ushort f2bf(float f) {
  union { float f; unsigned int i; } v; v.f = f;
  unsigned int u = v.i;
  return (ushort)((u + 0x7FFFu + ((u >> 16) & 1u)) >> 16);
}
__device__ __forceinline__ float redgrp(float v) {
  v += __shfl_xor(v, 16); v += __shfl_xor(v, 32); return v;
}

// async global->LDS DMA, 16B per lane (wave-uniform LDS base + lane*16)
__device__ __forceinline__ void ldsdma16(const void* g, void* l) {
  __builtin_amdgcn_global_load_lds(
      (const __attribute__((address_space(1))) void*)g,
      (__attribute__((address_space(3))) void*)l, 16, 0, 0);
}

// BN scale/shift coefs from raw (sum,sumsq) stats. t<128 participates.
__device__ __forceinline__ void bn_coefs(const float* __restrict__ stats,
                                         const float* __restrict__ gamma,
                                         const float* __restrict__ beta,
                                         float inv_n, float* cA, float* cC, int t) {
  if (t < HDIM) {
    float s  = stats[t];
    float ss = stats[HDIM + t];
    float m  = s * inv_n;
    float var = fmaxf(ss * inv_n - m * m, 0.f);
    float a = gamma[t] * rsqrtf(var + BN_EPS);
    cA[t] = a;
    cC[t] = beta[t] - m * a;
  }
}

// Transpose + bf16-convert the 7 weight matrices into wt[m][n][k].
__global__ __launch_bounds__(256, 2)
void k_prep(const float* __restrict__ w_lin_start, const float* __restrict__ w_conv1,
            const float* __restrict__ w_conv2, ushort* __restrict__ wt) {
  __shared__ ushort T[128 * 136];
  const int m = blockIdx.x;      // 0: lin_start, 1..3: conv_w1, 4..6: conv_w2
  const int t = threadIdx.x;
  const float* W = (m == 0) ? w_lin_start
                 : (m <= 3) ? w_conv1 + (size_t)(m - 1) * HDIM * HDIM
                            : w_conv2 + (size_t)(m - 4) * HDIM * HDIM;
  for (int it = 0; it < 64; ++it) {
    int idx = it * 256 + t;          // W row-major [k][n]
    int k = idx >> 7, n = idx & 127;
    T[k * 136 + n] = f2bf(W[idx]);
  }
  __syncthreads();
  ushort* o = wt + (size_t)m * HDIM * HDIM;  // [n][k]
  for (int it = 0; it < 64; ++it) {
    int idx = it * 256 + t;
    int n = idx >> 7, k = idx & 127;
    o[idx] = T[k * 136 + n];
  }
}

// out[128rows x 128] = (act(in) @ W) + bias via bf16 MFMA; col stats -> outStats.
// 512 thr = 8 waves x 16 rows. A: reg-staged (act/cvt folded) into swizzled LDS
// tile; B: global_load_lds DMA from Wt[n][k] into swizzled LDS tile. XOR swizzle
// chunk^=(row&7) on both (256B row stride would be 32-way conflict otherwise).
template <int ACT, int FP32IN>
__global__ __launch_bounds__(512, 4)
void k_mm(const void* __restrict__ in_v, ushort* __restrict__ out,
          const ushort* __restrict__ Wt, const float* __restrict__ bias,
          const float* __restrict__ actStats, const float* __restrict__ actG,
          const float* __restrict__ actB, float act_inv_n,
          float* __restrict__ outStats) {
  __shared__ ushort At[HDIM * HDIM];   // 32 KB, [row][swchunk*8]
  __shared__ ushort Bt[HDIM * HDIM];   // 32 KB, [col][swchunk*8]
  __shared__ float biasL[HDIM];
  __shared__ float sred[2 * HDIM];
  __shared__ float aA[HDIM], aC[HDIM];
  const int t = threadIdx.x;
  const int lane = t & 63;
  const int w = t >> 6;        // wave 0..7
  const int lr = lane & 15;
  const int lg = lane >> 4;    // 0..3

  // --- B staging via LDS-DMA (4 issues, each wave: 4 cols x 16 chunks) ---
  #pragma unroll
  for (int is = 0; is < 4; ++is) {
    const int col = is * 32 + w * 4 + (lane >> 4);
    const int sc  = lane & 15;
    const int gsc = sc ^ (col & 7);
    ldsdma16(Wt + (size_t)col * HDIM + gsc * 8, &Bt[(is * 512 + w * 64) * 8]);
  }

  // --- A staging: 4 chunks/thread, global->reg (+act/cvt) -> swizzled ds_write ---
  if (ACT) bn_coefs(actStats, actG, actB, act_inv_n, aA, aC, t);
  if (t < HDIM) biasL[t] = bias[t];
  if (t < 2 * HDIM) sred[t] = 0.f;
  if (ACT) __syncthreads();  // aA/aC ready before use below

  const size_t blkRow0 = (size_t)blockIdx.x * 128;
  const float*  inF = (const float*)in_v;
  const ushort* inB = (const ushort*)in_v;
  #pragma unroll
  for (int is = 0; is < 4; ++is) {
    const int cid = is * 512 + t;
    const int row = cid >> 4, sc = cid & 15;
    bf16x8 a;
    if (FP32IN) {
      const float* gp = inF + (blkRow0 + row) * HDIM + sc * 8;
      float4 v0 = *(const float4*)gp;
      float4 v1 = *(const float4*)(gp + 4);
      a[0] = (short)f2bf(v0.x); a[1] = (short)f2bf(v0.y);
      a[2] = (short)f2bf(v0.z); a[3] = (short)f2bf(v0.w);
      a[4] = (short)f2bf(v1.x); a[5] = (short)f2bf(v1.y);
      a[6] = (short)f2bf(v1.z); a[7] = (short)f2bf(v1.w);
    } else {
      a = *(const bf16x8*)(inB + (blkRow0 + row) * HDIM + sc * 8);
      if (ACT) {
        const int k0 = sc * 8;
        #pragma unroll
        for (int j = 0; j < 8; ++j) {
          float f = fmaxf(fmaf(aA[k0 + j], bf2f((ushort)a[j]), aC[k0 + j]), 0.f);
          a[j] = (short)f2bf(f);
        }
      }
    }
    *(bf16x8*)&At[row * HDIM + (sc ^ (row & 7)) * 8] = a;
  }
  __syncthreads();

  // --- k-loop: all operands from LDS ---
  f32x4 acc[8];
  #pragma unroll
  for (int cf = 0; cf < 8; ++cf) acc[cf] = (f32x4){0.f, 0.f, 0.f, 0.f};

  const int rowL = w * 16 + lr;   // wave's A row (local)
  #pragma unroll
  for (int ks = 0; ks < 4; ++ks) {
    const int c = ks * 4 + lg;                    // k-chunk 0..15
    const int swc = c ^ (lr & 7);                 // row&7 == col&7 == lr&7
    bf16x8 afr = *(const bf16x8*)&At[rowL * HDIM + swc * 8];
    #pragma unroll
    for (int cf = 0; cf < 8; ++cf) {
      const int col = cf * 16 + lr;
      bf16x8 bfr = *(const bf16x8*)&Bt[col * HDIM + swc * 8];
      acc[cf] = __builtin_amdgcn_mfma_f32_16x16x32_bf16(afr, bfr, acc[cf], 0, 0, 0);
    }
  }

  // --- epilogue: bias, bf16 store, column stats (D: col=lr, row=lg*4+r) ---
  #pragma unroll
  for (int cf = 0; cf < 8; ++cf) {
    const int col = cf * 16 + lr;
    const float bia = biasL[col];
    float s = 0.f, qq = 0.f;
    const size_t rowb = blkRow0 + w * 16 + lg * 4;
    #pragma unroll
    for (int r = 0; r < 4; ++r) {
      float y = acc[cf][r] + bia;
      out[(rowb + r) * HDIM + col] = f2bf(y);
      s += y; qq += y * y;
    }
    s = redgrp(s); qq = redgrp(qq);
    if (lg == 0) { atomicAdd(&sred[col], s); atomicAdd(&sred[HDIM + col], qq); }
  }
  __syncthreads();
  if (t < 2 * HDIM) atomicAdd(&outStats[t], sred[t]);
}

// Per-graph GIN aggregation on bf16 node features (f32 LDS internally).
template <int NPG>
__global__ __launch_bounds__(512, 2)
void k_agg(const ushort* __restrict__ xin_g, ushort* __restrict__ hout,
           const int* __restrict__ esrc, const int* __restrict__ edst,
           int shift,
           const float* __restrict__ actStats, const float* __restrict__ actG,
           const float* __restrict__ actB, float act_inv_n) {
  __shared__ float xs[NPG * HDIM];
  __shared__ int   srcs[EPG];
  __shared__ int   cnt[NPG], off[NPG], cur[NPG], scn[NPG];
  __shared__ float aA[HDIM], aC[HDIM];
  const int t = threadIdx.x;
  const int g = blockIdx.x;
  const bool act = (actStats != nullptr);

  int myd[4], mys[4];
  const int ebase = g * EPG;
  #pragma unroll
  for (int u = 0; u < 4; ++u) {
    const int e = ebase + t + u * 512;
    myd[u] = (edst[e] >> shift) - g * NPG;
    mys[u] = (esrc[e] >> shift) - g * NPG;
  }

  if (act) bn_coefs(actStats, actG, actB, act_inv_n, aA, aC, t);
  if (t < NPG) { cnt[t] = 0; cur[t] = 0; }
  __syncthreads();

  const ushort* xg = xin_g + (size_t)g * NPG * HDIM;
  float4* xs4 = (float4*)xs;
  for (int u = t; u < NPG * 16; u += 512) {
    bf16x8 v = *(const bf16x8*)(xg + u * 8);
    const int c0 = (u & 15) * 8;
    float f[8];
    #pragma unroll
    for (int j = 0; j < 8; ++j) {
      f[j] = bf2f((ushort)v[j]);
      if (act) f[j] = fmaxf(fmaf(aA[c0 + j], f[j], aC[c0 + j]), 0.f);
    }
    xs4[u * 2 + 0] = make_float4(f[0], f[1], f[2], f[3]);
    xs4[u * 2 + 1] = make_float4(f[4], f[5], f[6], f[7]);
  }
  #pragma unroll
  for (int u = 0; u < 4; ++u) atomicAdd(&cnt[myd[u]], 1);
  __syncthreads();

  if (t < NPG) scn[t] = cnt[t];
  __syncthreads();
  #pragma unroll
  for (int s = 1; s < NPG; s <<= 1) {
    int v = (t < NPG && t >= s) ? scn[t - s] : 0;
    __syncthreads();
    if (t < NPG) scn[t] += v;
    __syncthreads();
  }
  if (t < NPG) off[t] = scn[t] - cnt[t];
  __syncthreads();

  #pragma unroll
  for (int u = 0; u < 4; ++u) {
    int p = off[myd[u]] + atomicAdd(&cur[myd[u]], 1);
    srcs[p] = mys[u];
  }
  __syncthreads();

  const int c4 = t & 31;
  const int dg = t >> 5;
  ushort* hb = hout + (size_t)g * NPG * HDIM;
  for (int d = dg; d < NPG; d += 16) {
    float4 acc = xs4[d * 32 + c4];
    int e = off[d];
    const int e2 = e + cnt[d];
    for (; e + 4 <= e2; e += 4) {
      const int s0 = srcs[e], s1 = srcs[e + 1], s2 = srcs[e + 2], s3 = srcs[e + 3];
      float4 v0 = xs4[s0 * 32 + c4];
      float4 v1 = xs4[s1 * 32 + c4];
      float4 v2 = xs4[s2 * 32 + c4];
      float4 v3 = xs4[s3 * 32 + c4];
      acc.x += (v0.x + v1.x) + (v2.x + v3.x);
      acc.y += (v0.y + v1.y) + (v2.y + v3.y);
      acc.z += (v0.z + v1.z) + (v2.z + v3.z);
      acc.w += (v0.w + v1.w) + (v2.w + v3.w);
    }
    for (; e < e2; ++e) {
      float4 v = xs4[srcs[e] * 32 + c4];
      acc.x += v.x; acc.y += v.y; acc.z += v.z; acc.w += v.w;
    }
    ushort4 hv;
    hv.x = f2bf(acc.x); hv.y = f2bf(acc.y); hv.z = f2bf(acc.z); hv.w = f2bf(acc.w);
    *(ushort4*)&hb[d * HDIM + c4 * 4] = hv;
  }
}

// x' = haar(act(h)) ; emb[g] ; embd col-stats. bf16 in/out, emb f32.
__global__ __launch_bounds__(256, 4)
void k_pool(const ushort* __restrict__ hin, ushort* __restrict__ xout,
            float* __restrict__ emb, int layer, int npg_in,
            const float* __restrict__ actStats, const float* __restrict__ actG,
            const float* __restrict__ actB, float act_inv_n,
            float* __restrict__ embStats) {
  __shared__ float aA[HDIM], aC[HDIM];
  __shared__ float red[256];
  const int t = threadIdx.x;
  const int g = blockIdx.x;
  bn_coefs(actStats, actG, actB, act_inv_n, aA, aC, t);
  __syncthreads();
  const int c = t & 127;
  const int ph = t >> 7;
  const int npg_out = npg_in >> 1;
  const ushort* hb = hin + (size_t)g * npg_in * HDIM;
  ushort* xb = xout + (size_t)g * npg_out * HDIM;
  const float a = aA[c], cc = aC[c];
  float es = 0.f;
  for (int p = ph; p < npg_out; p += 2) {
    float v0 = fmaxf(fmaf(a, bf2f(hb[(2 * p    ) * HDIM + c]), cc), 0.f);
    float v1 = fmaxf(fmaf(a, bf2f(hb[(2 * p + 1) * HDIM + c]), cc), 0.f);
    float xv = (v0 + v1) * INV_SQRT2;
    xb[p * HDIM + c] = f2bf(xv);
    es += xv;
  }
  red[t] = es;
  __syncthreads();
  if (t < HDIM) {
    float e = red[t] + red[t + HDIM];
    emb[(size_t)g * 384 + layer * HDIM + t] = e;
    atomicAdd(&embStats[t], e);
    atomicAdd(&embStats[HDIM + t], e * e);
  }
}

__global__ __launch_bounds__(128, 8)
void k_final(const float* __restrict__ emb,
             const float* __restrict__ se0, const float* __restrict__ se1,
             const float* __restrict__ se2,
             const float* __restrict__ bneG, const float* __restrict__ bneB,
             const float* __restrict__ linW, const float* __restrict__ linB,
             float* __restrict__ outp) {
  __shared__ float ev[384];
  __shared__ float eA[384], eC[384];
  const int t = threadIdx.x;
  const int g = blockIdx.x;
  if (t < 128) {
    const float* se[3] = {se0, se1, se2};
    const float inv_n = 1.f / (float)G_GRAPHS;
    #pragma unroll
    for (int l = 0; l < 3; ++l) {
      float s  = se[l][t];
      float ss = se[l][128 + t];
      float m  = s * inv_n;
      float var = fmaxf(ss * inv_n - m * m, 0.f);
      float a = bneG[l * 128 + t] * rsqrtf(var + BN_EPS);
      eA[l * 128 + t] = a;
      eC[l * 128 + t] = bneB[l * 128 + t] - m * a;
    }
  }
  __syncthreads();
  for (int j = t; j < 384; j += 128)
    ev[j] = fmaxf(fmaf(eA[j], emb[(size_t)g * 384 + j], eC[j]), 0.f);
  __syncthreads();
  if (t < 10) {
    float acc = linB[t];
    #pragma unroll 8
    for (int j = 0; j < 384; ++j) acc += ev[j] * linW[j * 10 + t];
    outp[g * 10 + t] = acc;
  }
}

extern "C" void kernel_launch(void* const* d_in, const int* in_sizes, int n_in,
                              void* d_out, int out_size, void* d_ws, size_t ws_size,
                              hipStream_t stream) {
  const float* x           = (const float*)d_in[0];
  const int*   ei          = (const int*)  d_in[1];
  const float* lin_start_w = (const float*)d_in[2];
  const float* lin_start_b = (const float*)d_in[3];
  const float* bn_start_g  = (const float*)d_in[4];
  const float* bn_start_b  = (const float*)d_in[5];
  const float* conv_w1     = (const float*)d_in[6];
  const float* conv_b1     = (const float*)d_in[7];
  const float* conv_bn_g   = (const float*)d_in[8];
  const float* conv_bn_b   = (const float*)d_in[9];
  const float* conv_w2     = (const float*)d_in[10];
  const float* conv_b2     = (const float*)d_in[11];
  const float* bn_g        = (const float*)d_in[12];
  const float* bn_b        = (const float*)d_in[13];
  const float* bne_g       = (const float*)d_in[14];
  const float* bne_b       = (const float*)d_in[15];
  const float* lin_w       = (const float*)d_in[16];
  const float* lin_b       = (const float*)d_in[17];
  float* outp = (float*)d_out;

  const size_t NH = (size_t)N_NODES * HDIM;
  float*  stats = (float*)d_ws;                       // 10 slots * 256
  float*  emb   = stats + 10 * 256;                   // G * 384
  ushort* wt    = (ushort*)(emb + (size_t)G_GRAPHS * 384);  // 7 * 128 * 128
  ushort* buf0  = wt + 7 * HDIM * HDIM;
  ushort* buf1  = buf0 + NH;

  hipMemsetAsync(stats, 0, 10 * 256 * sizeof(float), stream);

  const int* esrc = ei;
  const int* edst = ei + E_EDGES;

  k_prep<<<7, 256, 0, stream>>>(lin_start_w, conv_w1, conv_w2, wt);

  // y0 = x @ lin_start_w + b (stats -> slot 0)
  k_mm<0, 1><<<N_NODES / 128, 512, 0, stream>>>(
      x, buf0, wt, lin_start_b, nullptr, nullptr, nullptr, 0.f, stats);

  for (int i = 0; i < 3; ++i) {
    const int n = N_NODES >> i;
    const float inv_n = 1.f / (float)n;
    float* s1 = stats + (1 + 3 * i) * 256;
    float* s2 = stats + (2 + 3 * i) * 256;
    float* se = stats + (3 + 3 * i) * 256;
    const ushort* wt1 = wt + (size_t)(1 + i) * HDIM * HDIM;
    const ushort* wt2 = wt + (size_t)(4 + i) * HDIM * HDIM;

    const float* aS = (i == 0) ? stats : nullptr;
    if (i == 0)
      k_agg<128><<<G_GRAPHS, 512, 0, stream>>>(buf0, buf1, esrc, edst, 0,
          aS, bn_start_g, bn_start_b, 1.f / (float)N_NODES);
    else if (i == 1)
      k_agg<64><<<G_GRAPHS, 512, 0, stream>>>(buf0, buf1, esrc, edst, 1,
          aS, bn_start_g, bn_start_b, 1.f / (float)N_NODES);
    else
      k_agg<32><<<G_GRAPHS, 512, 0, stream>>>(buf0, buf1, esrc, edst, 2,
          aS, bn_start_g, bn_start_b, 1.f / (float)N_NODES);

    // h1 = h @ w1 + b1 (stats -> s1)
    k_mm<0, 0><<<n / 128, 512, 0, stream>>>(
        buf1, buf0, wt1, conv_b1 + i * HDIM, nullptr, nullptr, nullptr, 0.f, s1);
    // h2 = relu(bn(h1)) @ w2 + b2 (stats -> s2)
    k_mm<1, 0><<<n / 128, 512, 0, stream>>>(
        buf0, buf1, wt2, conv_b2 + i * HDIM,
        s1, conv_bn_g + i * HDIM, conv_bn_b + i * HDIM, inv_n, s2);
    // x' = haar(relu(bn(h2))) ; emb col i ; embd stats -> se
    k_pool<<<G_GRAPHS, 256, 0, stream>>>(
        buf1, buf0, emb, i, NPG0 >> i,
        s2, bn_g + i * HDIM, bn_b + i * HDIM, inv_n, se);
  }

  k_final<<<G_GRAPHS, 128, 0, stream>>>(
      emb, stats + 3 * 256, stats + 6 * 256, stats + 9 * 256,
      bne_g, bne_b, lin_w, lin_b, outp);
}